// Round 4
// baseline (792.115 us; speedup 1.0000x reference)
//
#include <hip/hip_runtime.h>

typedef unsigned short u16;
typedef unsigned int   u32;
typedef __bf16 bf16x8 __attribute__((ext_vector_type(8)));
typedef float  f32x4  __attribute__((ext_vector_type(4)));

// ---- problem constants ----
#define BSZ   4096
#define NK    16
#define IN1   160        // 128 obs + 32 act
#define H1D   1024
#define H2D   1024
#define K1MAIN 2560      // NK*IN1
#define K1P    2624      // pad to 41*64  (2560 + 16 bias + 48 zero)
#define K2MAIN 16384     // NK*H1D
#define K2P    16448     // pad to 257*64 (16384 + 16 bias + 48 zero)

// ---- helpers ----
// Compiler cast -> v_cvt_pk_bf16_f32 pairing (m240: faster than manual RNE bit-twiddle)
__device__ __forceinline__ u16 f2bf(float f) {
    __bf16 h = (__bf16)f;
    return __builtin_bit_cast(u16, h);
}
__device__ __forceinline__ u32 pack2bf(float lo, float hi) {
    return (u32)f2bf(lo) | ((u32)f2bf(hi) << 16);
}
__device__ __forceinline__ float bflo(u32 u) { return __uint_as_float(u << 16); }
__device__ __forceinline__ float bfhi(u32 u) { return __uint_as_float(u & 0xFFFF0000u); }

__device__ __forceinline__ void gload16(const void* g, void* l) {
    __builtin_amdgcn_global_load_lds(
        (const __attribute__((address_space(1))) unsigned int*)g,
        (__attribute__((address_space(3))) unsigned int*)l, 16, 0, 0);
}

// ---- transpose+convert: out[n][kap] = W[kap][n] (fp32->bf16), bias rows appended, zero pad ----
__global__ void transpose_conv_kernel(const float* __restrict__ W,
                                      const float* __restrict__ bias,
                                      u16* __restrict__ outw,
                                      int Kdim, int KP)
{
    __shared__ float lt[64][65];
    const int k0 = blockIdx.x * 64, n0 = blockIdx.y * 64;
    const int c = threadIdx.x & 63, r0 = threadIdx.x >> 6;
#pragma unroll
    for (int rr = 0; rr < 16; ++rr) {
        const int r = r0 + rr * 4;
        const int kap = k0 + r;
        float v = 0.0f;
        if (kap < Kdim)            v = W[(size_t)kap * 1024 + n0 + c];
        else if (kap < Kdim + NK)  v = bias[(size_t)(kap - Kdim) * 1024 + n0 + c];
        lt[r][c] = v;
    }
    __syncthreads();
#pragma unroll
    for (int it = 0; it < 2; ++it) {
        const int q = it * 256 + threadIdx.x;
        const int nl = q >> 3, kc = q & 7;
        uint4 o;
        o.x = pack2bf(lt[kc * 8 + 0][nl], lt[kc * 8 + 1][nl]);
        o.y = pack2bf(lt[kc * 8 + 2][nl], lt[kc * 8 + 3][nl]);
        o.z = pack2bf(lt[kc * 8 + 4][nl], lt[kc * 8 + 5][nl]);
        o.w = pack2bf(lt[kc * 8 + 6][nl], lt[kc * 8 + 7][nl]);
        *reinterpret_cast<uint4*>(&outw[(size_t)(n0 + nl) * KP + k0 + kc * 8]) = o;
    }
}

// ---- GEMM: C[4096 x 1024] = A[4096 x KP] * B^T[1024 x KP]^T, relu epilogue ----
// MODE_A==0: A is a materialized bf16 matrix (global_load_lds staging)
// MODE_A==1: A is the fused X2 expansion: A[b, k*1024+j] = cw[b,k]*h1[b,j] (reg-staged)
// MODE_A==2: A is the fused X1 expansion: A[b, k*160+i] = cw[b,k]*x[b,i], x=[obs|act]
// Tiles: BM=128, BN=64, BK=64. 4 waves (2x2), each owns 64x32. grid = 32*16 = 512.
template <int MODE_A, int STORE_F32>
__global__ __launch_bounds__(256, 2)
void gemm_kernel(const u16* __restrict__ Ag,
                 const u16* __restrict__ h1,
                 const float* __restrict__ obs,
                 const float* __restrict__ act,
                 const float* __restrict__ cw,
                 const u16* __restrict__ Bt,
                 void* __restrict__ outp,
                 int KP, int ksteps, int Kmain)
{
    __shared__ u16 lA[128 * 64];   // 16 KB, XOR-swizzled layout
    __shared__ u16 lB[64 * 64];    //  8 KB

    const int tid = threadIdx.x;
    const int wv = tid >> 6, lane = tid & 63;
    const int l15 = lane & 15, lg = lane >> 4;
    const int bid = blockIdx.x;
    const int ntile = bid & 15, mtile = bid >> 4;   // consecutive bids share the A panel
    const int brow = mtile * 128, bcol = ntile * 64;
    const int wr = (wv >> 1) * 64, wc = (wv & 1) * 32;

    f32x4 acc[4][2];
#pragma unroll
    for (int i = 0; i < 4; ++i)
#pragma unroll
        for (int j = 0; j < 2; ++j) acc[i][j] = (f32x4){0.f, 0.f, 0.f, 0.f};

    for (int kt = 0; kt < ksteps; ++kt) {
        __syncthreads();
        // ---- stage A tile [128 rows][64 k] ----
        if (MODE_A == 0) {
#pragma unroll
            for (int it = 0; it < 4; ++it) {
                const int c = it * 256 + tid;
                const int row = c >> 3, kb = (c & 7) << 4;
                const int kbS = kb ^ ((row & 7) << 4);       // pre-swizzled source
                gload16(Ag + (size_t)(brow + row) * KP + kt * 64 + (kbS >> 1),
                        &lA[(it * 256 + (wv << 6)) * 8]);
            }
        } else if (MODE_A == 1) {
#pragma unroll
            for (int it = 0; it < 4; ++it) {
                const int c = it * 256 + tid;
                const int row = c >> 3, kb = (c & 7) << 4;
                const int lkb = kb ^ ((row & 7) << 4);       // logical col for this slot
                const int b_ = brow + row;
                uint4 dat;
                const int kap0 = kt * 64;
                if (kap0 < Kmain) {
                    const int k = kap0 >> 10;                // 64 | 1024 -> k uniform per tile
                    const int j = (kap0 & 1023) + (lkb >> 1);
                    const float s = cw[b_ * NK + k];
                    uint4 h = *reinterpret_cast<const uint4*>(&h1[(size_t)b_ * 1024 + j]);
                    dat.x = pack2bf(bflo(h.x) * s, bfhi(h.x) * s);
                    dat.y = pack2bf(bflo(h.y) * s, bfhi(h.y) * s);
                    dat.z = pack2bf(bflo(h.z) * s, bfhi(h.z) * s);
                    dat.w = pack2bf(bflo(h.w) * s, bfhi(h.w) * s);
                } else {
                    const int base = lkb >> 1;               // bias cols: kap-Kmain = base+e
                    u16 v[8];
#pragma unroll
                    for (int e = 0; e < 8; ++e) {
                        const int kk2 = base + e;
                        v[e] = (kk2 < NK) ? f2bf(cw[b_ * NK + kk2]) : (u16)0;
                    }
                    dat.x = (u32)v[0] | ((u32)v[1] << 16);
                    dat.y = (u32)v[2] | ((u32)v[3] << 16);
                    dat.z = (u32)v[4] | ((u32)v[5] << 16);
                    dat.w = (u32)v[6] | ((u32)v[7] << 16);
                }
                *reinterpret_cast<uint4*>(&lA[row * 64 + (kb >> 1)]) = dat;
            }
        } else {  // MODE_A == 2 : fused X1 build. 8-elem runs never straddle k (160%8==0)
                  // or the obs/act split (128%8==0); branch is per-run.
#pragma unroll
            for (int it = 0; it < 4; ++it) {
                const int c = it * 256 + tid;
                const int row = c >> 3, kb = (c & 7) << 4;
                const int lkb = kb ^ ((row & 7) << 4);       // logical col for this slot
                const int b_ = brow + row;
                uint4 dat;
                const int kap = kt * 64 + (lkb >> 1);
                if (kap < Kmain) {
                    const int k = kap / IN1;
                    const int i = kap - k * IN1;
                    const float s = cw[b_ * NK + k];
                    const float* src = (i < 128) ? (obs + (size_t)b_ * 128 + i)
                                                 : (act + (size_t)b_ * 32 + (i - 128));
                    float4 f0 = *reinterpret_cast<const float4*>(src);
                    float4 f1 = *reinterpret_cast<const float4*>(src + 4);
                    dat.x = pack2bf(f0.x * s, f0.y * s);
                    dat.y = pack2bf(f0.z * s, f0.w * s);
                    dat.z = pack2bf(f1.x * s, f1.y * s);
                    dat.w = pack2bf(f1.z * s, f1.w * s);
                } else {
                    const int base = kap - Kmain;            // bias cols
                    u16 v[8];
#pragma unroll
                    for (int e = 0; e < 8; ++e) {
                        const int kk2 = base + e;
                        v[e] = (kk2 < NK) ? f2bf(cw[b_ * NK + kk2]) : (u16)0;
                    }
                    dat.x = (u32)v[0] | ((u32)v[1] << 16);
                    dat.y = (u32)v[2] | ((u32)v[3] << 16);
                    dat.z = (u32)v[4] | ((u32)v[5] << 16);
                    dat.w = (u32)v[6] | ((u32)v[7] << 16);
                }
                *reinterpret_cast<uint4*>(&lA[row * 64 + (kb >> 1)]) = dat;
            }
        }
        // ---- stage B tile [64 rows(n)][64 k] ----
#pragma unroll
        for (int it = 0; it < 2; ++it) {
            const int c = it * 256 + tid;
            const int row = c >> 3, kb = (c & 7) << 4;
            const int kbS = kb ^ ((row & 7) << 4);
            gload16(Bt + (size_t)(bcol + row) * KP + kt * 64 + (kbS >> 1),
                    &lB[(it * 256 + (wv << 6)) * 8]);
        }
        __syncthreads();
        // ---- compute: 2 k-slices of 32 ----
#pragma unroll
        for (int kk = 0; kk < 2; ++kk) {
            bf16x8 af[4];
            bf16x8 bfr[2];
            const int kbyte = (kk << 6) | (lg << 4);
#pragma unroll
            for (int mi = 0; mi < 4; ++mi) {
                const int r = wr + mi * 16 + l15;
                const int sl = kbyte ^ ((r & 7) << 4);
                af[mi] = *reinterpret_cast<const bf16x8*>(&lA[r * 64 + (sl >> 1)]);
            }
#pragma unroll
            for (int ni = 0; ni < 2; ++ni) {
                const int r = wc + ni * 16 + l15;
                const int sl = kbyte ^ ((r & 7) << 4);
                bfr[ni] = *reinterpret_cast<const bf16x8*>(&lB[r * 64 + (sl >> 1)]);
            }
#pragma unroll
            for (int mi = 0; mi < 4; ++mi)
#pragma unroll
                for (int ni = 0; ni < 2; ++ni)
                    acc[mi][ni] = __builtin_amdgcn_mfma_f32_16x16x32_bf16(
                        af[mi], bfr[ni], acc[mi][ni], 0, 0, 0);
        }
    }
    // ---- epilogue: relu, store ----
#pragma unroll
    for (int mi = 0; mi < 4; ++mi)
#pragma unroll
        for (int ni = 0; ni < 2; ++ni)
#pragma unroll
            for (int r = 0; r < 4; ++r) {
                float v = acc[mi][ni][r];
                v = fmaxf(v, 0.0f);
                const int gm = brow + wr + mi * 16 + lg * 4 + r;
                const int gn = bcol + wc + ni * 16 + l15;
                if (STORE_F32)
                    ((float*)outp)[(size_t)gm * 1024 + gn] = v;
                else
                    ((u16*)outp)[(size_t)gm * 1024 + gn] = f2bf(v);
            }
}

// ---- final GEMV: out[b] = h2[b,:] . Wo + bo ----
__global__ void gemv_out_kernel(const float* __restrict__ h2,
                                const float* __restrict__ Wo,
                                const float* __restrict__ bo,
                                float* __restrict__ out)
{
    const int wv = threadIdx.x >> 6, lane = threadIdx.x & 63;
    const int row = blockIdx.x * 4 + wv;
    const float* hr = h2 + (size_t)row * 1024;
    float s = 0.0f;
#pragma unroll
    for (int i = 0; i < 4; ++i) {
        float4 h = *reinterpret_cast<const float4*>(hr + lane * 4 + i * 256);
        float4 w = *reinterpret_cast<const float4*>(Wo + lane * 4 + i * 256);
        s += h.x * w.x + h.y * w.y + h.z * w.z + h.w * w.w;
    }
#pragma unroll
    for (int off = 32; off; off >>= 1) s += __shfl_xor(s, off, 64);
    if (lane == 0) out[row] = s + bo[0];
}

extern "C" void kernel_launch(void* const* d_in, const int* in_sizes, int n_in,
                              void* d_out, int out_size, void* d_ws, size_t ws_size,
                              hipStream_t stream)
{
    const float* obs = (const float*)d_in[0];
    const float* act = (const float*)d_in[1];
    const float* cw  = (const float*)d_in[2];
    const float* W1  = (const float*)d_in[3];
    const float* b1  = (const float*)d_in[4];
    const float* W2  = (const float*)d_in[5];
    const float* b2  = (const float*)d_in[6];
    const float* Wo  = (const float*)d_in[7];
    const float* bo  = (const float*)d_in[8];

    char* ws = (char*)d_ws;
    u16* W1T = (u16*)ws;                                  // 1024*2624  bf16  (5.4 MB)
    u16* W2T = W1T + (size_t)H1D * K1P;                   // 1024*16448 bf16  (33.7 MB)
    u16* H1  = W2T + (size_t)H2D * K2P;                   // 4096*1024  bf16  (8.4 MB)
    float* H2 = (float*)(H1 + (size_t)BSZ * H1D);         // 4096*1024  fp32  (16.8 MB)
    // total ws use ~64.2 MB

    transpose_conv_kernel<<<dim3(K1P / 64, 16), 256, 0, stream>>>(W1, b1, W1T, K1MAIN, K1P);
    transpose_conv_kernel<<<dim3(K2P / 64, 16), 256, 0, stream>>>(W2, b2, W2T, K2MAIN, K2P);

    gemm_kernel<2, 0><<<512, 256, 0, stream>>>(nullptr, nullptr, obs, act, cw, W1T, H1,
                                               K1P, K1P / 64, K1MAIN);
    gemm_kernel<1, 1><<<512, 256, 0, stream>>>(nullptr, H1, nullptr, nullptr, cw, W2T, H2,
                                               K2P, K2P / 64, K2MAIN);

    gemv_out_kernel<<<BSZ / 4, 256, 0, stream>>>(H2, Wo, bo, (float*)d_out);
}

// Round 5
// 425.017 us; speedup vs baseline: 1.8637x; 1.8637x over previous
//
#include <hip/hip_runtime.h>

typedef unsigned short u16;
typedef unsigned int   u32;
typedef __bf16 bf16x8 __attribute__((ext_vector_type(8)));
typedef float  f32x4  __attribute__((ext_vector_type(4)));

// ---- problem constants ----
#define BSZ   4096
#define NK    16
#define IN1   160        // 128 obs + 32 act
#define H1D   1024
#define H2D   1024
#define K1MAIN 2560      // NK*IN1
#define K1P    2624      // pad to 41*64  (2560 + 16 bias + 48 zero)
#define K2P    16384     // NK*H1D exact (bias folded into accumulator scaling)

// ---- helpers ----
__device__ __forceinline__ u16 f2bf(float f) {
    __bf16 h = (__bf16)f;
    return __builtin_bit_cast(u16, h);
}
__device__ __forceinline__ u32 pack2bf(float lo, float hi) {
    return (u32)f2bf(lo) | ((u32)f2bf(hi) << 16);
}

__device__ __forceinline__ void gload16(const void* g, void* l) {
    __builtin_amdgcn_global_load_lds(
        (const __attribute__((address_space(1))) unsigned int*)g,
        (__attribute__((address_space(3))) unsigned int*)l, 16, 0, 0);
}

// ---- transpose+convert: out[n][kap] = W[kap][n] (fp32->bf16), optional bias rows, zero pad ----
__global__ void transpose_conv_kernel(const float* __restrict__ W,
                                      const float* __restrict__ bias,
                                      u16* __restrict__ outw,
                                      int Kdim, int KP)
{
    __shared__ float lt[64][65];
    const int k0 = blockIdx.x * 64, n0 = blockIdx.y * 64;
    const int c = threadIdx.x & 63, r0 = threadIdx.x >> 6;
#pragma unroll
    for (int rr = 0; rr < 16; ++rr) {
        const int r = r0 + rr * 4;
        const int kap = k0 + r;
        float v = 0.0f;
        if (kap < Kdim)            v = W[(size_t)kap * 1024 + n0 + c];
        else if (kap < Kdim + NK)  v = bias[(size_t)(kap - Kdim) * 1024 + n0 + c];
        lt[r][c] = v;
    }
    __syncthreads();
#pragma unroll
    for (int it = 0; it < 2; ++it) {
        const int q = it * 256 + threadIdx.x;
        const int nl = q >> 3, kc = q & 7;
        uint4 o;
        o.x = pack2bf(lt[kc * 8 + 0][nl], lt[kc * 8 + 1][nl]);
        o.y = pack2bf(lt[kc * 8 + 2][nl], lt[kc * 8 + 3][nl]);
        o.z = pack2bf(lt[kc * 8 + 4][nl], lt[kc * 8 + 5][nl]);
        o.w = pack2bf(lt[kc * 8 + 6][nl], lt[kc * 8 + 7][nl]);
        *reinterpret_cast<uint4*>(&outw[(size_t)(n0 + nl) * KP + k0 + kc * 8]) = o;
    }
}

// ============================================================================
// GEMM1: H1[4096 x 1024] = relu( X1 * W1T^T ), X1[b, k*160+i] = cw[b,k]*x[b,i]
// fused in registers. BM=128,BN=64,BK=64, 4 waves, 2-phase double-buffer.
// ============================================================================
__global__ __launch_bounds__(256, 2)
void gemm1_kernel(const float* __restrict__ obs,
                  const float* __restrict__ act,
                  const float* __restrict__ cw,
                  const u16* __restrict__ Bt,     // W1T [1024][K1P]
                  u16* __restrict__ H1)
{
    __shared__ u16 lA[2][128 * 64];
    __shared__ u16 lB[2][64 * 64];

    const int tid = threadIdx.x;
    const int wv = tid >> 6, lane = tid & 63;
    const int l15 = lane & 15, lg = lane >> 4;
    const int bid = blockIdx.x;
    const int ntile = bid & 15, mtile = bid >> 4;
    const int brow = mtile * 128, bcol = ntile * 64;
    const int wr = (wv >> 1) * 64, wc = (wv & 1) * 32;

    f32x4 acc[4][2];
#pragma unroll
    for (int i = 0; i < 4; ++i)
#pragma unroll
        for (int j = 0; j < 2; ++j) acc[i][j] = (f32x4){0.f, 0.f, 0.f, 0.f};

    // ---- staging lambdas ----
    auto stageA = [&](int kt, int buf) {   // fused X1 build (reg-staged)
#pragma unroll
        for (int it = 0; it < 4; ++it) {
            const int c = it * 256 + tid;
            const int row = c >> 3, kb = (c & 7) << 4;
            const int lkb = kb ^ ((row & 7) << 4);   // logical col for this slot
            const int b_ = brow + row;
            uint4 dat;
            const int kap = kt * 64 + (lkb >> 1);
            if (kap < K1MAIN) {
                const int k = kap / IN1;
                const int i = kap - k * IN1;
                const float s = cw[b_ * NK + k];
                const float* src = (i < 128) ? (obs + (size_t)b_ * 128 + i)
                                             : (act + (size_t)b_ * 32 + (i - 128));
                float4 f0 = *reinterpret_cast<const float4*>(src);
                float4 f1 = *reinterpret_cast<const float4*>(src + 4);
                dat.x = pack2bf(f0.x * s, f0.y * s);
                dat.y = pack2bf(f0.z * s, f0.w * s);
                dat.z = pack2bf(f1.x * s, f1.y * s);
                dat.w = pack2bf(f1.z * s, f1.w * s);
            } else {
                const int base = kap - K1MAIN;       // bias cols (cw), then zeros
                u16 v[8];
#pragma unroll
                for (int e = 0; e < 8; ++e) {
                    const int kk2 = base + e;
                    v[e] = (kk2 < NK) ? f2bf(cw[b_ * NK + kk2]) : (u16)0;
                }
                dat.x = (u32)v[0] | ((u32)v[1] << 16);
                dat.y = (u32)v[2] | ((u32)v[3] << 16);
                dat.z = (u32)v[4] | ((u32)v[5] << 16);
                dat.w = (u32)v[6] | ((u32)v[7] << 16);
            }
            *reinterpret_cast<uint4*>(&lA[buf][row * 64 + (kb >> 1)]) = dat;
        }
    };
    auto stageB = [&](int kt, int buf) {
#pragma unroll
        for (int it = 0; it < 2; ++it) {
            const int c = it * 256 + tid;
            const int row = c >> 3, kb = (c & 7) << 4;
            const int kbS = kb ^ ((row & 7) << 4);   // pre-swizzled source
            gload16(Bt + (size_t)(bcol + row) * K1P + kt * 64 + (kbS >> 1),
                    &lB[buf][(it * 256 + (wv << 6)) * 8]);
        }
    };

    const int ksteps = K1P / 64;   // 41
    stageA(0, 0);
    stageB(0, 0);
    __syncthreads();
    int cur = 0;
    for (int kt = 0; kt < ksteps; ++kt) {
        if (kt + 1 < ksteps) { stageB(kt + 1, cur ^ 1); stageA(kt + 1, cur ^ 1); }
        // ---- compute from buf cur ----
#pragma unroll
        for (int kk = 0; kk < 2; ++kk) {
            bf16x8 af[4];
            bf16x8 bfr[2];
            const int kbyte = (kk << 6) | (lg << 4);
#pragma unroll
            for (int mi = 0; mi < 4; ++mi) {
                const int r = wr + mi * 16 + l15;
                const int sl = kbyte ^ ((r & 7) << 4);
                af[mi] = *reinterpret_cast<const bf16x8*>(&lA[cur][r * 64 + (sl >> 1)]);
            }
#pragma unroll
            for (int ni = 0; ni < 2; ++ni) {
                const int r = wc + ni * 16 + l15;
                const int sl = kbyte ^ ((r & 7) << 4);
                bfr[ni] = *reinterpret_cast<const bf16x8*>(&lB[cur][r * 64 + (sl >> 1)]);
            }
#pragma unroll
            for (int mi = 0; mi < 4; ++mi)
#pragma unroll
                for (int ni = 0; ni < 2; ++ni)
                    acc[mi][ni] = __builtin_amdgcn_mfma_f32_16x16x32_bf16(
                        af[mi], bfr[ni], acc[mi][ni], 0, 0, 0);
        }
        __syncthreads();
        cur ^= 1;
    }
    // ---- epilogue: relu -> bf16 ----
#pragma unroll
    for (int mi = 0; mi < 4; ++mi)
#pragma unroll
        for (int ni = 0; ni < 2; ++ni)
#pragma unroll
            for (int r = 0; r < 4; ++r) {
                float v = fmaxf(acc[mi][ni][r], 0.0f);
                const int gm = brow + wr + mi * 16 + lg * 4 + r;
                const int gn = bcol + wc + ni * 16 + l15;
                H1[(size_t)gm * 1024 + gn] = f2bf(v);
            }
}

// ============================================================================
// GEMM2: H2[4096 x 1024] = relu( sum_k cw[b,k] * (H1 . W2[k] + b2[k]) )
// Unscaled partial product per k-group (16 ksteps = one k), cw applied to the
// fp32 accumulator at group end (bias folded there too). A staged directly
// from H1 via global_load_lds (no VALU pack). 2-phase double-buffer.
// ============================================================================
__global__ __launch_bounds__(256, 2)
void gemm2_kernel(const u16* __restrict__ h1,    // [4096][1024] bf16
                  const float* __restrict__ cw,  // [4096][16]
                  const float* __restrict__ b2,  // [16][1024]
                  const u16* __restrict__ Bt,    // W2T [1024][16384] bf16
                  float* __restrict__ H2)
{
    __shared__ u16 lA[2][128 * 64];
    __shared__ u16 lB[2][64 * 64];

    const int tid = threadIdx.x;
    const int wv = tid >> 6, lane = tid & 63;
    const int l15 = lane & 15, lg = lane >> 4;
    const int bid = blockIdx.x;
    const int ntile = bid & 15, mtile = bid >> 4;   // same-ntile blocks land on same XCD
    const int brow = mtile * 128, bcol = ntile * 64;
    const int wr = (wv >> 1) * 64, wc = (wv & 1) * 32;

    f32x4 part[4][2], master[4][2];
#pragma unroll
    for (int i = 0; i < 4; ++i)
#pragma unroll
        for (int j = 0; j < 2; ++j) {
            part[i][j] = (f32x4){0.f, 0.f, 0.f, 0.f};
            master[i][j] = (f32x4){0.f, 0.f, 0.f, 0.f};
        }

    auto stageA = [&](int kt, int buf) {   // direct from h1, pre-swizzled source
        const int j0 = (kt & 15) * 64;
#pragma unroll
        for (int it = 0; it < 4; ++it) {
            const int c = it * 256 + tid;
            const int row = c >> 3, kb = (c & 7) << 4;
            const int kbS = kb ^ ((row & 7) << 4);
            gload16(h1 + (size_t)(brow + row) * 1024 + j0 + (kbS >> 1),
                    &lA[buf][(it * 256 + (wv << 6)) * 8]);
        }
    };
    auto stageB = [&](int kt, int buf) {
#pragma unroll
        for (int it = 0; it < 2; ++it) {
            const int c = it * 256 + tid;
            const int row = c >> 3, kb = (c & 7) << 4;
            const int kbS = kb ^ ((row & 7) << 4);
            gload16(Bt + (size_t)(bcol + row) * K2P + kt * 64 + (kbS >> 1),
                    &lB[buf][(it * 256 + (wv << 6)) * 8]);
        }
    };

    float cwv[4][4];   // cw[gm, kg] for this thread's 16 output rows
    float b2v[2];      // b2[kg, gn] for this thread's 2 output cols

    const int ksteps = K2P / 64;   // 256, k-group = 16 ksteps
    stageB(0, 0);
    stageA(0, 0);
    __syncthreads();
    int cur = 0;
    for (int kt = 0; kt < ksteps; ++kt) {
        if (kt + 1 < ksteps) { stageB(kt + 1, cur ^ 1); stageA(kt + 1, cur ^ 1); }
        if ((kt & 15) == 0) {          // prefetch scale factors for this k-group
            const int kg = kt >> 4;
#pragma unroll
            for (int mi = 0; mi < 4; ++mi)
#pragma unroll
                for (int r = 0; r < 4; ++r)
                    cwv[mi][r] = cw[(brow + wr + mi * 16 + lg * 4 + r) * NK + kg];
#pragma unroll
            for (int ni = 0; ni < 2; ++ni)
                b2v[ni] = b2[kg * 1024 + bcol + wc + ni * 16 + l15];
        }
        // ---- compute from buf cur ----
#pragma unroll
        for (int kk = 0; kk < 2; ++kk) {
            bf16x8 af[4];
            bf16x8 bfr[2];
            const int kbyte = (kk << 6) | (lg << 4);
#pragma unroll
            for (int mi = 0; mi < 4; ++mi) {
                const int r = wr + mi * 16 + l15;
                const int sl = kbyte ^ ((r & 7) << 4);
                af[mi] = *reinterpret_cast<const bf16x8*>(&lA[cur][r * 64 + (sl >> 1)]);
            }
#pragma unroll
            for (int ni = 0; ni < 2; ++ni) {
                const int r = wc + ni * 16 + l15;
                const int sl = kbyte ^ ((r & 7) << 4);
                bfr[ni] = *reinterpret_cast<const bf16x8*>(&lB[cur][r * 64 + (sl >> 1)]);
            }
#pragma unroll
            for (int mi = 0; mi < 4; ++mi)
#pragma unroll
                for (int ni = 0; ni < 2; ++ni)
                    part[mi][ni] = __builtin_amdgcn_mfma_f32_16x16x32_bf16(
                        af[mi], bfr[ni], part[mi][ni], 0, 0, 0);
        }
        if ((kt & 15) == 15) {         // fold k-group into master: cw*(part + b2)
#pragma unroll
            for (int mi = 0; mi < 4; ++mi)
#pragma unroll
                for (int ni = 0; ni < 2; ++ni)
#pragma unroll
                    for (int r = 0; r < 4; ++r) {
                        master[mi][ni][r] += cwv[mi][r] * (part[mi][ni][r] + b2v[ni]);
                        part[mi][ni][r] = 0.0f;
                    }
        }
        __syncthreads();
        cur ^= 1;
    }
    // ---- epilogue: relu -> fp32 ----
#pragma unroll
    for (int mi = 0; mi < 4; ++mi)
#pragma unroll
        for (int ni = 0; ni < 2; ++ni)
#pragma unroll
            for (int r = 0; r < 4; ++r) {
                float v = fmaxf(master[mi][ni][r], 0.0f);
                const int gm = brow + wr + mi * 16 + lg * 4 + r;
                const int gn = bcol + wc + ni * 16 + l15;
                H2[(size_t)gm * 1024 + gn] = v;
            }
}

// ---- final GEMV: out[b] = h2[b,:] . Wo + bo ----
__global__ void gemv_out_kernel(const float* __restrict__ h2,
                                const float* __restrict__ Wo,
                                const float* __restrict__ bo,
                                float* __restrict__ out)
{
    const int wv = threadIdx.x >> 6, lane = threadIdx.x & 63;
    const int row = blockIdx.x * 4 + wv;
    const float* hr = h2 + (size_t)row * 1024;
    float s = 0.0f;
#pragma unroll
    for (int i = 0; i < 4; ++i) {
        float4 h = *reinterpret_cast<const float4*>(hr + lane * 4 + i * 256);
        float4 w = *reinterpret_cast<const float4*>(Wo + lane * 4 + i * 256);
        s += h.x * w.x + h.y * w.y + h.z * w.z + h.w * w.w;
    }
#pragma unroll
    for (int off = 32; off; off >>= 1) s += __shfl_xor(s, off, 64);
    if (lane == 0) out[row] = s + bo[0];
}

extern "C" void kernel_launch(void* const* d_in, const int* in_sizes, int n_in,
                              void* d_out, int out_size, void* d_ws, size_t ws_size,
                              hipStream_t stream)
{
    const float* obs = (const float*)d_in[0];
    const float* act = (const float*)d_in[1];
    const float* cw  = (const float*)d_in[2];
    const float* W1  = (const float*)d_in[3];
    const float* b1  = (const float*)d_in[4];
    const float* W2  = (const float*)d_in[5];
    const float* b2  = (const float*)d_in[6];
    const float* Wo  = (const float*)d_in[7];
    const float* bo  = (const float*)d_in[8];

    char* ws = (char*)d_ws;
    u16* W1T = (u16*)ws;                                  // 1024*2624  bf16  (5.4 MB)
    u16* W2T = W1T + (size_t)H1D * K1P;                   // 1024*16384 bf16  (33.6 MB)
    u16* H1  = W2T + (size_t)H2D * K2P;                   // 4096*1024  bf16  (8.4 MB)
    float* H2 = (float*)(H1 + (size_t)BSZ * H1D);         // 4096*1024  fp32  (16.8 MB)
    // total ws use ~64.2 MB

    transpose_conv_kernel<<<dim3(K1P / 64, 16), 256, 0, stream>>>(W1, b1, W1T, K1MAIN, K1P);
    transpose_conv_kernel<<<dim3(K2P / 64, 16), 256, 0, stream>>>(W2, b2, W2T, K2P, K2P);

    gemm1_kernel<<<512, 256, 0, stream>>>(obs, act, cw, W1T, H1);
    gemm2_kernel<<<512, 256, 0, stream>>>(H1, cw, b2, W2T, H2);

    gemv_out_kernel<<<BSZ / 4, 256, 0, stream>>>(H2, Wo, bo, (float*)d_out);
}

// Round 6
// 357.021 us; speedup vs baseline: 2.2187x; 1.1905x over previous
//
#include <hip/hip_runtime.h>

typedef unsigned short u16;
typedef unsigned int   u32;
typedef __bf16 bf16x8 __attribute__((ext_vector_type(8)));
typedef float  f32x4  __attribute__((ext_vector_type(4)));

// ---- problem constants ----
#define BSZ   4096
#define NK    16
#define IN1   160        // 128 obs + 32 act
#define H1D   1024
#define H2D   1024
#define K1MAIN 2560      // NK*IN1
#define K1P    2624      // pad to 41*64  (2560 + 16 bias + 48 zero)
#define K2P    16384     // NK*H1D exact (bias folded into accumulator scaling)

// ---- helpers ----
__device__ __forceinline__ u16 f2bf(float f) {
    __bf16 h = (__bf16)f;
    return __builtin_bit_cast(u16, h);
}
__device__ __forceinline__ u32 pack2bf(float lo, float hi) {
    return (u32)f2bf(lo) | ((u32)f2bf(hi) << 16);
}

__device__ __forceinline__ void gload16(const void* g, void* l) {
    __builtin_amdgcn_global_load_lds(
        (const __attribute__((address_space(1))) unsigned int*)g,
        (__attribute__((address_space(3))) unsigned int*)l, 16, 0, 0);
}

// ---- transpose+convert: out[n][kap] = W[kap][n] (fp32->bf16), optional bias rows, zero pad ----
__global__ void transpose_conv_kernel(const float* __restrict__ W,
                                      const float* __restrict__ bias,
                                      u16* __restrict__ outw,
                                      int Kdim, int KP)
{
    __shared__ float lt[64][65];
    const int k0 = blockIdx.x * 64, n0 = blockIdx.y * 64;
    const int c = threadIdx.x & 63, r0 = threadIdx.x >> 6;
#pragma unroll
    for (int rr = 0; rr < 16; ++rr) {
        const int r = r0 + rr * 4;
        const int kap = k0 + r;
        float v = 0.0f;
        if (kap < Kdim)            v = W[(size_t)kap * 1024 + n0 + c];
        else if (kap < Kdim + NK)  v = bias[(size_t)(kap - Kdim) * 1024 + n0 + c];
        lt[r][c] = v;
    }
    __syncthreads();
#pragma unroll
    for (int it = 0; it < 2; ++it) {
        const int q = it * 256 + threadIdx.x;
        const int nl = q >> 3, kc = q & 7;
        uint4 o;
        o.x = pack2bf(lt[kc * 8 + 0][nl], lt[kc * 8 + 1][nl]);
        o.y = pack2bf(lt[kc * 8 + 2][nl], lt[kc * 8 + 3][nl]);
        o.z = pack2bf(lt[kc * 8 + 4][nl], lt[kc * 8 + 5][nl]);
        o.w = pack2bf(lt[kc * 8 + 6][nl], lt[kc * 8 + 7][nl]);
        *reinterpret_cast<uint4*>(&outw[(size_t)(n0 + nl) * KP + k0 + kc * 8]) = o;
    }
}

// ============================================================================
// GEMM1: H1[4096 x 1024] = relu( X1 * W1T^T ), X1[b, k*160+i] = cw[b,k]*x[b,i]
// fused in registers. BM=128,BN=64,BK=64, 4 waves, 2-phase double-buffer.
// ============================================================================
__global__ __launch_bounds__(256, 2)
void gemm1_kernel(const float* __restrict__ obs,
                  const float* __restrict__ act,
                  const float* __restrict__ cw,
                  const u16* __restrict__ Bt,     // W1T [1024][K1P]
                  u16* __restrict__ H1)
{
    __shared__ u16 lA[2][128 * 64];
    __shared__ u16 lB[2][64 * 64];

    const int tid = threadIdx.x;
    const int wv = tid >> 6, lane = tid & 63;
    const int l15 = lane & 15, lg = lane >> 4;
    const int bid = blockIdx.x;
    const int ntile = bid & 15, mtile = bid >> 4;
    const int brow = mtile * 128, bcol = ntile * 64;
    const int wr = (wv >> 1) * 64, wc = (wv & 1) * 32;

    f32x4 acc[4][2];
#pragma unroll
    for (int i = 0; i < 4; ++i)
#pragma unroll
        for (int j = 0; j < 2; ++j) acc[i][j] = (f32x4){0.f, 0.f, 0.f, 0.f};

    auto stageA = [&](int kt, int buf) {   // fused X1 build (reg-staged)
#pragma unroll
        for (int it = 0; it < 4; ++it) {
            const int c = it * 256 + tid;
            const int row = c >> 3, kb = (c & 7) << 4;
            const int lkb = kb ^ ((row & 7) << 4);   // logical col for this slot
            const int b_ = brow + row;
            uint4 dat;
            const int kap = kt * 64 + (lkb >> 1);
            if (kap < K1MAIN) {
                const int k = kap / IN1;
                const int i = kap - k * IN1;
                const float s = cw[b_ * NK + k];
                const float* src = (i < 128) ? (obs + (size_t)b_ * 128 + i)
                                             : (act + (size_t)b_ * 32 + (i - 128));
                float4 f0 = *reinterpret_cast<const float4*>(src);
                float4 f1 = *reinterpret_cast<const float4*>(src + 4);
                dat.x = pack2bf(f0.x * s, f0.y * s);
                dat.y = pack2bf(f0.z * s, f0.w * s);
                dat.z = pack2bf(f1.x * s, f1.y * s);
                dat.w = pack2bf(f1.z * s, f1.w * s);
            } else {
                const int base = kap - K1MAIN;       // bias cols (cw), then zeros
                u16 v[8];
#pragma unroll
                for (int e = 0; e < 8; ++e) {
                    const int kk2 = base + e;
                    v[e] = (kk2 < NK) ? f2bf(cw[b_ * NK + kk2]) : (u16)0;
                }
                dat.x = (u32)v[0] | ((u32)v[1] << 16);
                dat.y = (u32)v[2] | ((u32)v[3] << 16);
                dat.z = (u32)v[4] | ((u32)v[5] << 16);
                dat.w = (u32)v[6] | ((u32)v[7] << 16);
            }
            *reinterpret_cast<uint4*>(&lA[buf][row * 64 + (kb >> 1)]) = dat;
        }
    };
    auto stageB = [&](int kt, int buf) {
#pragma unroll
        for (int it = 0; it < 2; ++it) {
            const int c = it * 256 + tid;
            const int row = c >> 3, kb = (c & 7) << 4;
            const int kbS = kb ^ ((row & 7) << 4);   // pre-swizzled source
            gload16(Bt + (size_t)(bcol + row) * K1P + kt * 64 + (kbS >> 1),
                    &lB[buf][(it * 256 + (wv << 6)) * 8]);
        }
    };

    const int ksteps = K1P / 64;   // 41
    stageA(0, 0);
    stageB(0, 0);
    __syncthreads();
    int cur = 0;
    for (int kt = 0; kt < ksteps; ++kt) {
        if (kt + 1 < ksteps) { stageB(kt + 1, cur ^ 1); stageA(kt + 1, cur ^ 1); }
#pragma unroll
        for (int kk = 0; kk < 2; ++kk) {
            bf16x8 af[4];
            bf16x8 bfr[2];
            const int kbyte = (kk << 6) | (lg << 4);
#pragma unroll
            for (int mi = 0; mi < 4; ++mi) {
                const int r = wr + mi * 16 + l15;
                const int sl = kbyte ^ ((r & 7) << 4);
                af[mi] = *reinterpret_cast<const bf16x8*>(&lA[cur][r * 64 + (sl >> 1)]);
            }
#pragma unroll
            for (int ni = 0; ni < 2; ++ni) {
                const int r = wc + ni * 16 + l15;
                const int sl = kbyte ^ ((r & 7) << 4);
                bfr[ni] = *reinterpret_cast<const bf16x8*>(&lB[cur][r * 64 + (sl >> 1)]);
            }
#pragma unroll
            for (int mi = 0; mi < 4; ++mi)
#pragma unroll
                for (int ni = 0; ni < 2; ++ni)
                    acc[mi][ni] = __builtin_amdgcn_mfma_f32_16x16x32_bf16(
                        af[mi], bfr[ni], acc[mi][ni], 0, 0, 0);
        }
        __syncthreads();
        cur ^= 1;
    }
#pragma unroll
    for (int mi = 0; mi < 4; ++mi)
#pragma unroll
        for (int ni = 0; ni < 2; ++ni)
#pragma unroll
            for (int r = 0; r < 4; ++r) {
                float v = fmaxf(acc[mi][ni][r], 0.0f);
                const int gm = brow + wr + mi * 16 + lg * 4 + r;
                const int gn = bcol + wc + ni * 16 + l15;
                H1[(size_t)gm * 1024 + gn] = f2bf(v);
            }
}

// ============================================================================
// GEMM2: partial[b,n] = sum_{k in chunk} cw[b,k] * (H1 . W2[k] + b2[k])
// BM=128, BN=128, BK=64, split-K=2 (8 k-groups per chunk). 4 waves (2x2),
// each wave owns 64x64. grid = 32*8*2 = 512 blocks, 64KB LDS -> 2 blocks/CU.
// Unscaled partial per k-group, cw folded on fp32 acc at group end.
// relu + chunk-sum deferred to gemv.
// ============================================================================
__global__ __launch_bounds__(256, 2)
void gemm2_kernel(const u16* __restrict__ h1,    // [4096][1024] bf16
                  const float* __restrict__ cw,  // [4096][16]
                  const float* __restrict__ b2,  // [16][1024]
                  const u16* __restrict__ Bt,    // W2T [1024][16384] bf16
                  float* __restrict__ H2a,
                  float* __restrict__ H2b)
{
    __shared__ u16 lA[2][128 * 64];
    __shared__ u16 lB[2][128 * 64];

    const int tid = threadIdx.x;
    const int wv = tid >> 6, lane = tid & 63;
    const int l15 = lane & 15, lg = lane >> 4;
    const int bid = blockIdx.x;
    const int kc = bid >> 8;                 // K-chunk 0/1 (slowest)
    const int r8 = bid & 255;
    const int ntile = r8 & 7, mtile = r8 >> 3;  // ntile -> XCD: one B panel per XCD
    const int brow = mtile * 128, bcol = ntile * 128;
    const int wr = (wv >> 1) * 64, wc = (wv & 1) * 64;
    const size_t kbase = (size_t)kc * 8192;

    f32x4 part[4][4], master[4][4];
#pragma unroll
    for (int i = 0; i < 4; ++i)
#pragma unroll
        for (int j = 0; j < 4; ++j) {
            part[i][j] = (f32x4){0.f, 0.f, 0.f, 0.f};
            master[i][j] = (f32x4){0.f, 0.f, 0.f, 0.f};
        }

    auto stageA = [&](int kt, int buf) {   // direct from h1, pre-swizzled source
        const int j0 = (kt & 15) * 64;     // h1 col within k-group
#pragma unroll
        for (int it = 0; it < 4; ++it) {
            const int c = it * 256 + tid;
            const int row = c >> 3, kb = (c & 7) << 4;
            const int kbS = kb ^ ((row & 7) << 4);
            gload16(h1 + (size_t)(brow + row) * 1024 + j0 + (kbS >> 1),
                    &lA[buf][(it * 256 + (wv << 6)) * 8]);
        }
    };
    auto stageB = [&](int kt, int buf) {
#pragma unroll
        for (int it = 0; it < 4; ++it) {
            const int c = it * 256 + tid;
            const int row = c >> 3, kb = (c & 7) << 4;
            const int kbS = kb ^ ((row & 7) << 4);
            gload16(Bt + (size_t)(bcol + row) * K2P + kbase + kt * 64 + (kbS >> 1),
                    &lB[buf][(it * 256 + (wv << 6)) * 8]);
        }
    };

    float cwv[4][4];   // cw[gm, kg] for this thread's 16 output rows
    float b2v[4];      // b2[kg, gn] for this thread's 4 output cols

    const int ksteps = 128;    // 8192 k per chunk, k-group = 16 ksteps
    stageB(0, 0);
    stageA(0, 0);
    __syncthreads();
    int cur = 0;
    for (int kt = 0; kt < ksteps; ++kt) {
        if (kt + 1 < ksteps) { stageB(kt + 1, cur ^ 1); stageA(kt + 1, cur ^ 1); }
        if ((kt & 15) == 0) {              // scale factors for this k-group
            const int kg = kc * 8 + (kt >> 4);
#pragma unroll
            for (int mi = 0; mi < 4; ++mi)
#pragma unroll
                for (int r = 0; r < 4; ++r)
                    cwv[mi][r] = cw[(brow + wr + mi * 16 + lg * 4 + r) * NK + kg];
#pragma unroll
            for (int ni = 0; ni < 4; ++ni)
                b2v[ni] = b2[kg * 1024 + bcol + wc + ni * 16 + l15];
        }
#pragma unroll
        for (int kk = 0; kk < 2; ++kk) {
            bf16x8 af[4];
            bf16x8 bfr[4];
            const int kbyte = (kk << 6) | (lg << 4);
#pragma unroll
            for (int mi = 0; mi < 4; ++mi) {
                const int r = wr + mi * 16 + l15;
                const int sl = kbyte ^ ((r & 7) << 4);
                af[mi] = *reinterpret_cast<const bf16x8*>(&lA[cur][r * 64 + (sl >> 1)]);
            }
#pragma unroll
            for (int ni = 0; ni < 4; ++ni) {
                const int r = wc + ni * 16 + l15;
                const int sl = kbyte ^ ((r & 7) << 4);
                bfr[ni] = *reinterpret_cast<const bf16x8*>(&lB[cur][r * 64 + (sl >> 1)]);
            }
#pragma unroll
            for (int mi = 0; mi < 4; ++mi)
#pragma unroll
                for (int ni = 0; ni < 4; ++ni)
                    part[mi][ni] = __builtin_amdgcn_mfma_f32_16x16x32_bf16(
                        af[mi], bfr[ni], part[mi][ni], 0, 0, 0);
        }
        if ((kt & 15) == 15) {             // fold k-group: master += cw*(part + b2)
#pragma unroll
            for (int mi = 0; mi < 4; ++mi)
#pragma unroll
                for (int ni = 0; ni < 4; ++ni)
#pragma unroll
                    for (int r = 0; r < 4; ++r) {
                        master[mi][ni][r] += cwv[mi][r] * (part[mi][ni][r] + b2v[ni]);
                        part[mi][ni][r] = 0.0f;
                    }
        }
        __syncthreads();
        cur ^= 1;
    }
    float* __restrict__ dst = kc ? H2b : H2a;
#pragma unroll
    for (int mi = 0; mi < 4; ++mi)
#pragma unroll
        for (int ni = 0; ni < 4; ++ni)
#pragma unroll
            for (int r = 0; r < 4; ++r) {
                const int gm = brow + wr + mi * 16 + lg * 4 + r;
                const int gn = bcol + wc + ni * 16 + l15;
                dst[(size_t)gm * 1024 + gn] = master[mi][ni][r];
            }
}

// ---- final GEMV: out[b] = relu(h2a[b,:]+h2b[b,:]) . Wo + bo ----
__global__ void gemv_out_kernel(const float* __restrict__ h2a,
                                const float* __restrict__ h2b,
                                const float* __restrict__ Wo,
                                const float* __restrict__ bo,
                                float* __restrict__ out)
{
    const int wv = threadIdx.x >> 6, lane = threadIdx.x & 63;
    const int row = blockIdx.x * 4 + wv;
    const float* ha = h2a + (size_t)row * 1024;
    const float* hb = h2b + (size_t)row * 1024;
    float s = 0.0f;
#pragma unroll
    for (int i = 0; i < 4; ++i) {
        float4 a = *reinterpret_cast<const float4*>(ha + lane * 4 + i * 256);
        float4 b = *reinterpret_cast<const float4*>(hb + lane * 4 + i * 256);
        float4 w = *reinterpret_cast<const float4*>(Wo + lane * 4 + i * 256);
        s += fmaxf(a.x + b.x, 0.f) * w.x + fmaxf(a.y + b.y, 0.f) * w.y
           + fmaxf(a.z + b.z, 0.f) * w.z + fmaxf(a.w + b.w, 0.f) * w.w;
    }
#pragma unroll
    for (int off = 32; off; off >>= 1) s += __shfl_xor(s, off, 64);
    if (lane == 0) out[row] = s + bo[0];
}

extern "C" void kernel_launch(void* const* d_in, const int* in_sizes, int n_in,
                              void* d_out, int out_size, void* d_ws, size_t ws_size,
                              hipStream_t stream)
{
    const float* obs = (const float*)d_in[0];
    const float* act = (const float*)d_in[1];
    const float* cw  = (const float*)d_in[2];
    const float* W1  = (const float*)d_in[3];
    const float* b1  = (const float*)d_in[4];
    const float* W2  = (const float*)d_in[5];
    const float* b2  = (const float*)d_in[6];
    const float* Wo  = (const float*)d_in[7];
    const float* bo  = (const float*)d_in[8];

    char* ws = (char*)d_ws;
    u16* W1T  = (u16*)ws;                                 // 1024*2624  bf16  (5.4 MB)
    u16* W2T  = W1T + (size_t)H1D * K1P;                  // 1024*16384 bf16  (33.6 MB)
    u16* H1   = W2T + (size_t)H2D * K2P;                  // 4096*1024  bf16  (8.4 MB)
    float* H2a = (float*)(H1 + (size_t)BSZ * H1D);        // 4096*1024  fp32  (16.8 MB)
    float* H2b = H2a + (size_t)BSZ * H2D;                 // 4096*1024  fp32  (16.8 MB)
    // total ws use ~81 MB

    transpose_conv_kernel<<<dim3(K1P / 64, 16), 256, 0, stream>>>(W1, b1, W1T, K1MAIN, K1P);
    transpose_conv_kernel<<<dim3(K2P / 64, 16), 256, 0, stream>>>(W2, b2, W2T, K2P, K2P);

    gemm1_kernel<<<512, 256, 0, stream>>>(obs, act, cw, W1T, H1);
    gemm2_kernel<<<512, 256, 0, stream>>>(H1, cw, b2, W2T, H2a, H2b);

    gemv_out_kernel<<<BSZ / 4, 256, 0, stream>>>(H2a, H2b, Wo, bo, (float*)d_out);
}

// Round 8
// 346.932 us; speedup vs baseline: 2.2832x; 1.0291x over previous
//
#include <hip/hip_runtime.h>

typedef unsigned short u16;
typedef unsigned int   u32;
typedef __bf16 bf16x8 __attribute__((ext_vector_type(8)));
typedef float  f32x4  __attribute__((ext_vector_type(4)));

// ---- problem constants ----
#define BSZ   4096
#define NK    16
#define IN1   160        // 128 obs + 32 act
#define H1D   1024
#define H2D   1024
#define K1MAIN 2560      // NK*IN1
#define K1P    2624      // pad to 41*64  (2560 + 16 bias + 48 zero)
#define K2P    16384     // NK*H1D exact (b2 folded at k-group boundary in gemm2)

// ---- helpers ----
__device__ __forceinline__ u16 f2bf(float f) {
    __bf16 h = (__bf16)f;
    return __builtin_bit_cast(u16, h);
}
__device__ __forceinline__ u32 pack2bf(float lo, float hi) {
    return (u32)f2bf(lo) | ((u32)f2bf(hi) << 16);
}
__device__ __forceinline__ float bflo(u32 u) { return __uint_as_float(u << 16); }
__device__ __forceinline__ float bfhi(u32 u) { return __uint_as_float(u & 0xFFFF0000u); }

__device__ __forceinline__ void gload16(const void* g, void* l) {
    __builtin_amdgcn_global_load_lds(
        (const __attribute__((address_space(1))) unsigned int*)g,
        (__attribute__((address_space(3))) unsigned int*)l, 16, 0, 0);
}

// ---- transpose+convert: out[n][kap] = W[kap][n] (fp32->bf16), optional bias rows, zero pad ----
__global__ void transpose_conv_kernel(const float* __restrict__ W,
                                      const float* __restrict__ bias,
                                      u16* __restrict__ outw,
                                      int Kdim, int KP)
{
    __shared__ float lt[64][65];
    const int k0 = blockIdx.x * 64, n0 = blockIdx.y * 64;
    const int c = threadIdx.x & 63, r0 = threadIdx.x >> 6;
#pragma unroll
    for (int rr = 0; rr < 16; ++rr) {
        const int r = r0 + rr * 4;
        const int kap = k0 + r;
        float v = 0.0f;
        if (kap < Kdim)            v = W[(size_t)kap * 1024 + n0 + c];
        else if (kap < Kdim + NK)  v = bias[(size_t)(kap - Kdim) * 1024 + n0 + c];
        lt[r][c] = v;
    }
    __syncthreads();
#pragma unroll
    for (int it = 0; it < 2; ++it) {
        const int q = it * 256 + threadIdx.x;
        const int nl = q >> 3, kc = q & 7;
        uint4 o;
        o.x = pack2bf(lt[kc * 8 + 0][nl], lt[kc * 8 + 1][nl]);
        o.y = pack2bf(lt[kc * 8 + 2][nl], lt[kc * 8 + 3][nl]);
        o.z = pack2bf(lt[kc * 8 + 4][nl], lt[kc * 8 + 5][nl]);
        o.w = pack2bf(lt[kc * 8 + 6][nl], lt[kc * 8 + 7][nl]);
        *reinterpret_cast<uint4*>(&outw[(size_t)(n0 + nl) * KP + k0 + kc * 8]) = o;
    }
}

// ============================================================================
// GEMM1: P_c[b,n] = X1[b, kchunk] . W1T[n, kchunk]^T  (partials, no relu)
// X1[b, k*160+i] = cw[b,k]*x[b,i] fused in registers; bias via cw cols.
// BM=128, BN=128, BK=64, split-K=2 (21/20 ksteps). 4 waves (2x2), wave owns
// 64x64. grid = 32*8*2 = 512 blocks, 64KB LDS -> 2 blocks/CU. 2-phase dbuf.
// (geometry cloned from the validated 157us gemm2)
// ============================================================================
__global__ __launch_bounds__(256, 2)
void gemm1_kernel(const float* __restrict__ obs,
                  const float* __restrict__ act,
                  const float* __restrict__ cw,
                  const u16* __restrict__ Bt,     // W1T [1024][K1P]
                  float* __restrict__ P0,
                  float* __restrict__ P1)
{
    __shared__ u16 lA[2][128 * 64];
    __shared__ u16 lB[2][128 * 64];

    const int tid = threadIdx.x;
    const int wv = tid >> 6, lane = tid & 63;
    const int l15 = lane & 15, lg = lane >> 4;
    const int bid = blockIdx.x;
    const int ntile = bid & 7, mtile = (bid >> 3) & 31, kc = bid >> 8;
    const int brow = mtile * 128, bcol = ntile * 128;
    const int wr = (wv >> 1) * 64, wc = (wv & 1) * 64;
    const int kt0 = kc ? 21 : 0, ktN = kc ? 41 : 21;

    f32x4 acc[4][4];
#pragma unroll
    for (int i = 0; i < 4; ++i)
#pragma unroll
        for (int j = 0; j < 4; ++j) acc[i][j] = (f32x4){0.f, 0.f, 0.f, 0.f};

    auto stageA = [&](int kt, int buf) {   // fused X1 build (reg-staged)
#pragma unroll
        for (int it = 0; it < 4; ++it) {
            const int c = it * 256 + tid;
            const int row = c >> 3, kb = (c & 7) << 4;
            const int lkb = kb ^ ((row & 7) << 4);   // logical col for this slot
            const int b_ = brow + row;
            uint4 dat;
            const int kap = kt * 64 + (lkb >> 1);
            if (kap < K1MAIN) {
                const int k = kap / IN1;
                const int i = kap - k * IN1;
                const float s = cw[b_ * NK + k];
                const float* src = (i < 128) ? (obs + (size_t)b_ * 128 + i)
                                             : (act + (size_t)b_ * 32 + (i - 128));
                float4 f0 = *reinterpret_cast<const float4*>(src);
                float4 f1 = *reinterpret_cast<const float4*>(src + 4);
                dat.x = pack2bf(f0.x * s, f0.y * s);
                dat.y = pack2bf(f0.z * s, f0.w * s);
                dat.z = pack2bf(f1.x * s, f1.y * s);
                dat.w = pack2bf(f1.z * s, f1.w * s);
            } else {
                const int base = kap - K1MAIN;       // bias cols (cw), then zeros
                u16 v[8];
#pragma unroll
                for (int e = 0; e < 8; ++e) {
                    const int kk2 = base + e;
                    v[e] = (kk2 < NK) ? f2bf(cw[b_ * NK + kk2]) : (u16)0;
                }
                dat.x = (u32)v[0] | ((u32)v[1] << 16);
                dat.y = (u32)v[2] | ((u32)v[3] << 16);
                dat.z = (u32)v[4] | ((u32)v[5] << 16);
                dat.w = (u32)v[6] | ((u32)v[7] << 16);
            }
            *reinterpret_cast<uint4*>(&lA[buf][row * 64 + (kb >> 1)]) = dat;
        }
    };
    auto stageB = [&](int kt, int buf) {
#pragma unroll
        for (int it = 0; it < 4; ++it) {
            const int c = it * 256 + tid;
            const int row = c >> 3, kb = (c & 7) << 4;
            const int kbS = kb ^ ((row & 7) << 4);   // pre-swizzled source
            gload16(Bt + (size_t)(bcol + row) * K1P + kt * 64 + (kbS >> 1),
                    &lB[buf][(it * 256 + (wv << 6)) * 8]);
        }
    };

    stageA(kt0, 0);
    stageB(kt0, 0);
    __syncthreads();
    int cur = 0;
    for (int kt = kt0; kt < ktN; ++kt) {
        if (kt + 1 < ktN) { stageB(kt + 1, cur ^ 1); stageA(kt + 1, cur ^ 1); }
#pragma unroll
        for (int kk = 0; kk < 2; ++kk) {
            bf16x8 af[4];
            bf16x8 bfr[4];
            const int kbyte = (kk << 6) | (lg << 4);
#pragma unroll
            for (int mi = 0; mi < 4; ++mi) {
                const int r = wr + mi * 16 + l15;
                const int sl = kbyte ^ ((r & 7) << 4);
                af[mi] = *reinterpret_cast<const bf16x8*>(&lA[cur][r * 64 + (sl >> 1)]);
            }
#pragma unroll
            for (int ni = 0; ni < 4; ++ni) {
                const int r = wc + ni * 16 + l15;
                const int sl = kbyte ^ ((r & 7) << 4);
                bfr[ni] = *reinterpret_cast<const bf16x8*>(&lB[cur][r * 64 + (sl >> 1)]);
            }
#pragma unroll
            for (int mi = 0; mi < 4; ++mi)
#pragma unroll
                for (int ni = 0; ni < 4; ++ni)
                    acc[mi][ni] = __builtin_amdgcn_mfma_f32_16x16x32_bf16(
                        af[mi], bfr[ni], acc[mi][ni], 0, 0, 0);
        }
        __syncthreads();
        cur ^= 1;
    }
    float* __restrict__ dst = kc ? P1 : P0;
#pragma unroll
    for (int mi = 0; mi < 4; ++mi)
#pragma unroll
        for (int ni = 0; ni < 4; ++ni)
#pragma unroll
            for (int r = 0; r < 4; ++r) {
                const int gm = brow + wr + mi * 16 + lg * 4 + r;
                const int gn = bcol + wc + ni * 16 + l15;
                dst[(size_t)gm * 1024 + gn] = acc[mi][ni][r];
            }
}

// ---- combine: H1 = bf16(relu(P0+P1)) ----
__global__ void combine_h1_kernel(const float* __restrict__ P0,
                                  const float* __restrict__ P1,
                                  u16* __restrict__ H1)
{
    const size_t base = ((size_t)blockIdx.x * 256 + threadIdx.x) * 8;
    float4 a0 = *reinterpret_cast<const float4*>(P0 + base);
    float4 a1 = *reinterpret_cast<const float4*>(P0 + base + 4);
    float4 b0 = *reinterpret_cast<const float4*>(P1 + base);
    float4 b1 = *reinterpret_cast<const float4*>(P1 + base + 4);
    uint4 o;
    o.x = pack2bf(fmaxf(a0.x + b0.x, 0.f), fmaxf(a0.y + b0.y, 0.f));
    o.y = pack2bf(fmaxf(a0.z + b0.z, 0.f), fmaxf(a0.w + b0.w, 0.f));
    o.z = pack2bf(fmaxf(a1.x + b1.x, 0.f), fmaxf(a1.y + b1.y, 0.f));
    o.w = pack2bf(fmaxf(a1.z + b1.z, 0.f), fmaxf(a1.w + b1.w, 0.f));
    *reinterpret_cast<uint4*>(&H1[base]) = o;
}

// ============================================================================
// GEMM2: partial[b,n] = sum_{k in chunk} cw[b,k] * (H1 . W2[k] + b2[k])
// BM=128, BN=128, BK=64, split-K=2 (8 k-groups per chunk). 4 waves (2x2),
// each wave owns 64x64. grid = 32*8*2 = 512 blocks, 64KB LDS -> 2 blocks/CU.
// Unscaled partial per k-group, cw folded on fp32 acc at group end.
// relu + chunk-sum deferred to gemv.  (validated at 157us, unchanged)
// ============================================================================
__global__ __launch_bounds__(256, 2)
void gemm2_kernel(const u16* __restrict__ h1,    // [4096][1024] bf16
                  const float* __restrict__ cw,  // [4096][16]
                  const float* __restrict__ b2,  // [16][1024]
                  const u16* __restrict__ Bt,    // W2T [1024][16384] bf16
                  float* __restrict__ H2a,
                  float* __restrict__ H2b)
{
    __shared__ u16 lA[2][128 * 64];
    __shared__ u16 lB[2][128 * 64];

    const int tid = threadIdx.x;
    const int wv = tid >> 6, lane = tid & 63;
    const int l15 = lane & 15, lg = lane >> 4;
    const int bid = blockIdx.x;
    const int kc = bid >> 8;                 // K-chunk 0/1 (slowest)
    const int r8 = bid & 255;
    const int ntile = r8 & 7, mtile = r8 >> 3;  // ntile -> XCD: one B panel per XCD
    const int brow = mtile * 128, bcol = ntile * 128;
    const int wr = (wv >> 1) * 64, wc = (wv & 1) * 64;
    const size_t kbase = (size_t)kc * 8192;

    f32x4 part[4][4], master[4][4];
#pragma unroll
    for (int i = 0; i < 4; ++i)
#pragma unroll
        for (int j = 0; j < 4; ++j) {
            part[i][j] = (f32x4){0.f, 0.f, 0.f, 0.f};
            master[i][j] = (f32x4){0.f, 0.f, 0.f, 0.f};
        }

    auto stageA = [&](int kt, int buf) {   // direct from h1, pre-swizzled source
        const int j0 = (kt & 15) * 64;     // h1 col within k-group
#pragma unroll
        for (int it = 0; it < 4; ++it) {
            const int c = it * 256 + tid;
            const int row = c >> 3, kb = (c & 7) << 4;
            const int kbS = kb ^ ((row & 7) << 4);
            gload16(h1 + (size_t)(brow + row) * 1024 + j0 + (kbS >> 1),
                    &lA[buf][(it * 256 + (wv << 6)) * 8]);
        }
    };
    auto stageB = [&](int kt, int buf) {
#pragma unroll
        for (int it = 0; it < 4; ++it) {
            const int c = it * 256 + tid;
            const int row = c >> 3, kb = (c & 7) << 4;
            const int kbS = kb ^ ((row & 7) << 4);
            gload16(Bt + (size_t)(bcol + row) * K2P + kbase + kt * 64 + (kbS >> 1),
                    &lB[buf][(it * 256 + (wv << 6)) * 8]);
        }
    };

    float cwv[4][4];   // cw[gm, kg] for this thread's 16 output rows
    float b2v[4];      // b2[kg, gn] for this thread's 4 output cols

    const int ksteps = 128;    // 8192 k per chunk, k-group = 16 ksteps
    stageB(0, 0);
    stageA(0, 0);
    __syncthreads();
    int cur = 0;
    for (int kt = 0; kt < ksteps; ++kt) {
        if (kt + 1 < ksteps) { stageB(kt + 1, cur ^ 1); stageA(kt + 1, cur ^ 1); }
        if ((kt & 15) == 0) {              // scale factors for this k-group
            const int kg = kc * 8 + (kt >> 4);
#pragma unroll
            for (int mi = 0; mi < 4; ++mi)
#pragma unroll
                for (int r = 0; r < 4; ++r)
                    cwv[mi][r] = cw[(brow + wr + mi * 16 + lg * 4 + r) * NK + kg];
#pragma unroll
            for (int ni = 0; ni < 4; ++ni)
                b2v[ni] = b2[kg * 1024 + bcol + wc + ni * 16 + l15];
        }
#pragma unroll
        for (int kk = 0; kk < 2; ++kk) {
            bf16x8 af[4];
            bf16x8 bfr[4];
            const int kbyte = (kk << 6) | (lg << 4);
#pragma unroll
            for (int mi = 0; mi < 4; ++mi) {
                const int r = wr + mi * 16 + l15;
                const int sl = kbyte ^ ((r & 7) << 4);
                af[mi] = *reinterpret_cast<const bf16x8*>(&lA[cur][r * 64 + (sl >> 1)]);
            }
#pragma unroll
            for (int ni = 0; ni < 4; ++ni) {
                const int r = wc + ni * 16 + l15;
                const int sl = kbyte ^ ((r & 7) << 4);
                bfr[ni] = *reinterpret_cast<const bf16x8*>(&lB[cur][r * 64 + (sl >> 1)]);
            }
#pragma unroll
            for (int mi = 0; mi < 4; ++mi)
#pragma unroll
                for (int ni = 0; ni < 4; ++ni)
                    part[mi][ni] = __builtin_amdgcn_mfma_f32_16x16x32_bf16(
                        af[mi], bfr[ni], part[mi][ni], 0, 0, 0);
        }
        if ((kt & 15) == 15) {             // fold k-group: master += cw*(part + b2)
#pragma unroll
            for (int mi = 0; mi < 4; ++mi)
#pragma unroll
                for (int ni = 0; ni < 4; ++ni)
#pragma unroll
                    for (int r = 0; r < 4; ++r) {
                        master[mi][ni][r] += cwv[mi][r] * (part[mi][ni][r] + b2v[ni]);
                        part[mi][ni][r] = 0.0f;
                    }
        }
        __syncthreads();
        cur ^= 1;
    }
    float* __restrict__ dst = kc ? H2b : H2a;
#pragma unroll
    for (int mi = 0; mi < 4; ++mi)
#pragma unroll
        for (int ni = 0; ni < 4; ++ni)
#pragma unroll
            for (int r = 0; r < 4; ++r) {
                const int gm = brow + wr + mi * 16 + lg * 4 + r;
                const int gn = bcol + wc + ni * 16 + l15;
                dst[(size_t)gm * 1024 + gn] = master[mi][ni][r];
            }
}

// ---- final GEMV: out[b] = relu(h2a[b,:]+h2b[b,:]) . Wo + bo ----
__global__ void gemv_out_kernel(const float* __restrict__ h2a,
                                const float* __restrict__ h2b,
                                const float* __restrict__ Wo,
                                const float* __restrict__ bo,
                                float* __restrict__ out)
{
    const int wv = threadIdx.x >> 6, lane = threadIdx.x & 63;
    const int row = blockIdx.x * 4 + wv;
    const float* ha = h2a + (size_t)row * 1024;
    const float* hb = h2b + (size_t)row * 1024;
    float s = 0.0f;
#pragma unroll
    for (int i = 0; i < 4; ++i) {
        float4 a = *reinterpret_cast<const float4*>(ha + lane * 4 + i * 256);
        float4 b = *reinterpret_cast<const float4*>(hb + lane * 4 + i * 256);
        float4 w = *reinterpret_cast<const float4*>(Wo + lane * 4 + i * 256);
        s += fmaxf(a.x + b.x, 0.f) * w.x + fmaxf(a.y + b.y, 0.f) * w.y
           + fmaxf(a.z + b.z, 0.f) * w.z + fmaxf(a.w + b.w, 0.f) * w.w;
    }
#pragma unroll
    for (int off = 32; off; off >>= 1) s += __shfl_xor(s, off, 64);
    if (lane == 0) out[row] = s + bo[0];
}

extern "C" void kernel_launch(void* const* d_in, const int* in_sizes, int n_in,
                              void* d_out, int out_size, void* d_ws, size_t ws_size,
                              hipStream_t stream)
{
    const float* obs = (const float*)d_in[0];
    const float* act = (const float*)d_in[1];
    const float* cw  = (const float*)d_in[2];
    const float* W1  = (const float*)d_in[3];
    const float* b1  = (const float*)d_in[4];
    const float* W2  = (const float*)d_in[5];
    const float* b2  = (const float*)d_in[6];
    const float* Wo  = (const float*)d_in[7];
    const float* bo  = (const float*)d_in[8];

    char* ws = (char*)d_ws;
    u16* W1T  = (u16*)ws;                                 // 1024*2624  bf16  (5.4 MB)
    u16* W2T  = W1T + (size_t)H1D * K1P;                  // 1024*16384 bf16  (33.6 MB)
    u16* H1   = W2T + (size_t)H2D * K2P;                  // 4096*1024  bf16  (8.4 MB)
    float* Pa = (float*)(H1 + (size_t)BSZ * H1D);         // 4096*1024  fp32  (16.8 MB)
    float* Pb = Pa + (size_t)BSZ * H2D;                   // 4096*1024  fp32  (16.8 MB)
    // total ws use ~81 MB (proven budget). Pa/Pb are reused: gemm1 partials ->
    // combine -> H1; then gemm2 partials -> gemv. Stream order makes this safe.

    transpose_conv_kernel<<<dim3(K1P / 64, 16), 256, 0, stream>>>(W1, b1, W1T, K1MAIN, K1P);
    transpose_conv_kernel<<<dim3(K2P / 64, 16), 256, 0, stream>>>(W2, b2, W2T, K2P, K2P);

    gemm1_kernel<<<512, 256, 0, stream>>>(obs, act, cw, W1T, Pa, Pb);
    combine_h1_kernel<<<BSZ * H1D / (256 * 8), 256, 0, stream>>>(Pa, Pb, H1);

    gemm2_kernel<<<512, 256, 0, stream>>>(H1, cw, b2, W2T, Pa, Pb);

    gemv_out_kernel<<<BSZ / 4, 256, 0, stream>>>(Pa, Pb, Wo, bo, (float*)d_out);
}